// Round 2
// baseline (5691.097 us; speedup 1.0000x reference)
//
#include <hip/hip_runtime.h>
#include <hip/hip_bf16.h>

#define NTOK 577
#define CH 768
#define NH 12
#define HD 64
#define M_ROWS 9232      // B * N
#define SPITCH 584       // 577 padded

__device__ __forceinline__ float bf2f(unsigned int u16) {
  union { unsigned int i; float f; } x; x.i = u16 << 16; return x.f;
}

// dtype-agnostic input load: f32 ? float : bf16
__device__ __forceinline__ float ldin(const void* p, size_t i, bool f32) {
  return f32 ? ((const float*)p)[i]
             : __bfloat162float(((const __hip_bfloat16*)p)[i]);
}

// ---- Kernel 0: detect input dtype. Read x as bf16 shorts at EVEN indices.
// If underlying data is fp32, even bf16s are fp32 low-mantissa halves ->
// uniform bit patterns -> ~46% have exponent >= 140 (|v|>=8192 or NaN/Inf).
// True bf16 N(0,1) data: zero such samples.
__global__ void detect_dtype(const unsigned short* __restrict__ xs,
                             int* __restrict__ flag) {
  __shared__ int cnt;
  if (threadIdx.x == 0) cnt = 0;
  __syncthreads();
  int local = 0;
  for (int i = threadIdx.x; i < 4096; i += 256) {
    unsigned int u = xs[2 * i];
    unsigned int e = (u >> 7) & 0xFFu;
    if (e >= 140u) local++;
  }
  atomicAdd(&cnt, local);
  __syncthreads();
  if (threadIdx.x == 0) *flag = (cnt > 100) ? 1 : 0;
}

// ---- Kernel 1: qkv = x @ Wqkv^T  (M=9232, K=768, N=2304), scatter to
// q,k,v laid out [b][h][n][d] bf16 (workspace, our format).
__global__ __launch_bounds__(256) void gemm_qkv(
    const void* __restrict__ X, const void* __restrict__ W,
    const int* __restrict__ flagp,
    __hip_bfloat16* __restrict__ q, __hip_bfloat16* __restrict__ k,
    __hip_bfloat16* __restrict__ v)
{
  const bool f32 = (*flagp != 0);
  __shared__ float As[16][65];
  __shared__ float Bs[16][65];
  const int m0 = blockIdx.y * 64;
  const int o0 = blockIdx.x * 64;
  const int tid = threadIdx.x;
  const int tx = tid & 15, ty = tid >> 4;
  const int lr = tid >> 2;          // 0..63
  const int lc = (tid & 3) << 2;    // 0,4,8,12
  float acc[4][4] = {};
  for (int k0 = 0; k0 < CH; k0 += 16) {
    int m = m0 + lr;
    if (m < M_ROWS) {
      size_t base = (size_t)m * CH + k0 + lc;
      #pragma unroll
      for (int j = 0; j < 4; ++j) As[lc + j][lr] = ldin(X, base + j, f32);
    } else {
      #pragma unroll
      for (int j = 0; j < 4; ++j) As[lc + j][lr] = 0.f;
    }
    size_t bbase = (size_t)(o0 + lr) * CH + k0 + lc;
    #pragma unroll
    for (int j = 0; j < 4; ++j) Bs[lc + j][lr] = ldin(W, bbase + j, f32);
    __syncthreads();
    #pragma unroll
    for (int kk = 0; kk < 16; ++kk) {
      float a[4], bb[4];
      #pragma unroll
      for (int i = 0; i < 4; ++i) a[i] = As[kk][ty * 4 + i];
      #pragma unroll
      for (int j = 0; j < 4; ++j) bb[j] = Bs[kk][tx * 4 + j];
      #pragma unroll
      for (int i = 0; i < 4; ++i)
        #pragma unroll
        for (int j = 0; j < 4; ++j) acc[i][j] += a[i] * bb[j];
    }
    __syncthreads();
  }
  #pragma unroll
  for (int i = 0; i < 4; ++i) {
    int m = m0 + ty * 4 + i;
    if (m >= M_ROWS) continue;
    int b = m / NTOK, n = m - b * NTOK;
    #pragma unroll
    for (int j = 0; j < 4; ++j) {
      int o = o0 + tx * 4 + j;
      int t = o / CH, rem = o - t * CH;
      int h = rem >> 6, dd = rem & 63;
      size_t dst = ((size_t)((b * NH + h) * NTOK + n)) * HD + dd;
      __hip_bfloat16 val = __float2bfloat16(acc[i][j]);
      if (t == 0) q[dst] = val; else if (t == 1) k[dst] = val; else v[dst] = val;
    }
  }
}

// ---- Kernel 2: fused talking-heads attention, one block per (b, n) query row.
// q/k/v are bf16 workspace (our own format). Wpre/Wpost are raw inputs (dual).
__global__ __launch_bounds__(256) void attn_fused(
    const __hip_bfloat16* __restrict__ q, const __hip_bfloat16* __restrict__ k,
    const __hip_bfloat16* __restrict__ v, const void* __restrict__ Wpre,
    const void* __restrict__ Wpost, const int* __restrict__ flagp,
    __hip_bfloat16* __restrict__ o1)
{
  const bool f32 = (*flagp != 0);
  __shared__ float S0[NH][SPITCH];
  __shared__ float S1[NH][SPITCH];
  __shared__ float qs[NH * HD];
  __shared__ float Wp[NH][NH];
  __shared__ float W2[NH][NH];
  __shared__ float rowsum[NH];
  const int tid = threadIdx.x;
  const int b = blockIdx.x / NTOK;
  const int n = blockIdx.x - b * NTOK;

  for (int i = tid; i < NH * HD; i += 256) {
    int h = i >> 6, dd = i & 63;
    qs[i] = __bfloat162float(q[((size_t)((b * NH + h) * NTOK + n)) * HD + dd]);
  }
  if (tid < NH * NH) Wp[tid / NH][tid % NH] = ldin(Wpre, tid, f32);
  __syncthreads();

  // phase 1: S0[h][m] = scale * q_h . k[b,h,m,:]
  for (int t = tid; t < NH * NTOK; t += 256) {
    int h = t / NTOK, m = t - h * NTOK;
    const uint4* kp = reinterpret_cast<const uint4*>(
        k + ((size_t)((b * NH + h) * NTOK + m)) * HD);
    const float* qh = qs + h * HD;
    float acc = 0.f;
    #pragma unroll
    for (int c = 0; c < 8; ++c) {
      uint4 u = kp[c];
      acc += qh[c*8+0]*bf2f(u.x & 0xffffu) + qh[c*8+1]*bf2f(u.x >> 16)
           + qh[c*8+2]*bf2f(u.y & 0xffffu) + qh[c*8+3]*bf2f(u.y >> 16)
           + qh[c*8+4]*bf2f(u.z & 0xffffu) + qh[c*8+5]*bf2f(u.z >> 16)
           + qh[c*8+6]*bf2f(u.w & 0xffffu) + qh[c*8+7]*bf2f(u.w >> 16);
    }
    S0[h][m] = acc * 0.125f;
  }
  __syncthreads();

  // phase 2: S1[g][m] = sum_h Wpre[g,h] * S0[h][m]
  for (int t = tid; t < NH * NTOK; t += 256) {
    int g = t / NTOK, m = t - g * NTOK;
    float acc = 0.f;
    #pragma unroll
    for (int h = 0; h < NH; ++h) acc += Wp[g][h] * S0[h][m];
    S1[g][m] = acc;
  }
  __syncthreads();

  // phase 3: per-row softmax (store exp, keep row sums)
  const int wave = tid >> 6, lane = tid & 63;
  for (int g = wave; g < NH; g += 4) {
    float mx = -1e30f;
    for (int m = lane; m < NTOK; m += 64) mx = fmaxf(mx, S1[g][m]);
    #pragma unroll
    for (int off = 32; off > 0; off >>= 1) mx = fmaxf(mx, __shfl_xor(mx, off));
    float sum = 0.f;
    for (int m = lane; m < NTOK; m += 64) {
      float e = __expf(S1[g][m] - mx);
      S1[g][m] = e; sum += e;
    }
    #pragma unroll
    for (int off = 32; off > 0; off >>= 1) sum += __shfl_xor(sum, off);
    if (lane == 0) rowsum[g] = sum;
  }
  __syncthreads();
  // fold 1/rowsum[h] into Wpost
  if (tid < NH * NH)
    W2[tid / NH][tid % NH] = ldin(Wpost, tid, f32) / rowsum[tid % NH];
  __syncthreads();

  // phase 4: S0[g][m] = sum_h W2[g,h] * S1[h][m]
  for (int t = tid; t < NH * NTOK; t += 256) {
    int g = t / NTOK, m = t - g * NTOK;
    float acc = 0.f;
    #pragma unroll
    for (int h = 0; h < NH; ++h) acc += W2[g][h] * S1[h][m];
    S0[g][m] = acc;
  }
  __syncthreads();

  // phase 5: o1[b,n,g*64+dd] = sum_m S0[g][m] * v[b,g,m,dd]
  #pragma unroll
  for (int r = 0; r < 3; ++r) {
    int cc = tid + r * 256;
    int g = cc >> 6, dd = cc & 63;
    const __hip_bfloat16* vp = v + ((size_t)((b * NH + g) * NTOK)) * HD + dd;
    float acc = 0.f;
    #pragma unroll 4
    for (int m = 0; m < NTOK; ++m)
      acc += S0[g][m] * __bfloat162float(vp[(size_t)m * HD]);
    o1[((size_t)(b * NTOK + n)) * CH + cc] = __float2bfloat16(acc);
  }
}

// ---- Kernel 3: out = o1 @ Wproj^T + bproj   (M=9232, K=768, N=768)
__global__ __launch_bounds__(256) void gemm_proj(
    const __hip_bfloat16* __restrict__ A, const void* __restrict__ W,
    const void* __restrict__ bias, const int* __restrict__ flagp,
    void* __restrict__ out)
{
  const bool f32 = (*flagp != 0);
  __shared__ float As[16][65];
  __shared__ float Bs[16][65];
  const int m0 = blockIdx.y * 64;
  const int o0 = blockIdx.x * 64;
  const int tid = threadIdx.x;
  const int tx = tid & 15, ty = tid >> 4;
  const int lr = tid >> 2;
  const int lc = (tid & 3) << 2;
  float acc[4][4] = {};
  for (int k0 = 0; k0 < CH; k0 += 16) {
    int m = m0 + lr;
    if (m < M_ROWS) {
      const __hip_bfloat16* s = A + (size_t)m * CH + k0 + lc;
      #pragma unroll
      for (int j = 0; j < 4; ++j) As[lc + j][lr] = __bfloat162float(s[j]);
    } else {
      #pragma unroll
      for (int j = 0; j < 4; ++j) As[lc + j][lr] = 0.f;
    }
    size_t bbase = (size_t)(o0 + lr) * CH + k0 + lc;
    #pragma unroll
    for (int j = 0; j < 4; ++j) Bs[lc + j][lr] = ldin(W, bbase + j, f32);
    __syncthreads();
    #pragma unroll
    for (int kk = 0; kk < 16; ++kk) {
      float a[4], bb[4];
      #pragma unroll
      for (int i = 0; i < 4; ++i) a[i] = As[kk][ty * 4 + i];
      #pragma unroll
      for (int j = 0; j < 4; ++j) bb[j] = Bs[kk][tx * 4 + j];
      #pragma unroll
      for (int i = 0; i < 4; ++i)
        #pragma unroll
        for (int j = 0; j < 4; ++j) acc[i][j] += a[i] * bb[j];
    }
    __syncthreads();
  }
  #pragma unroll
  for (int i = 0; i < 4; ++i) {
    int m = m0 + ty * 4 + i;
    if (m >= M_ROWS) continue;
    #pragma unroll
    for (int j = 0; j < 4; ++j) {
      int o = o0 + tx * 4 + j;
      float val = acc[i][j] + ldin(bias, o, f32);
      if (f32) ((float*)out)[(size_t)m * CH + o] = val;
      else ((__hip_bfloat16*)out)[(size_t)m * CH + o] = __float2bfloat16(val);
    }
  }
}

extern "C" void kernel_launch(void* const* d_in, const int* in_sizes, int n_in,
                              void* d_out, int out_size, void* d_ws, size_t ws_size,
                              hipStream_t stream) {
  const void* x     = d_in[0];
  const void* Wqkv  = d_in[1];
  const void* Wproj = d_in[2];
  const void* bproj = d_in[3];
  const void* Wpre  = d_in[4];
  const void* Wpost = d_in[5];

  int* flag = (int*)d_ws;
  const size_t SEG = (size_t)16 * NH * NTOK * HD;   // 7,090,176 elements
  __hip_bfloat16* ws = (__hip_bfloat16*)((char*)d_ws + 16);
  __hip_bfloat16* q  = ws;
  __hip_bfloat16* k  = ws + SEG;
  __hip_bfloat16* v  = ws + 2 * SEG;
  __hip_bfloat16* o1 = ws + 3 * SEG;

  dim3 blk(256);
  hipLaunchKernelGGL(detect_dtype, dim3(1), blk, 0, stream,
                     (const unsigned short*)x, flag);
  hipLaunchKernelGGL(gemm_qkv, dim3(36, 145), blk, 0, stream,
                     x, Wqkv, flag, q, k, v);
  hipLaunchKernelGGL(attn_fused, dim3(16 * NTOK), blk, 0, stream,
                     q, k, v, Wpre, Wpost, flag, o1);
  hipLaunchKernelGGL(gemm_proj, dim3(12, 145), blk, 0, stream,
                     o1, Wproj, bproj, flag, d_out);
}

// Round 3
// 1691.647 us; speedup vs baseline: 3.3642x; 3.3642x over previous
//
#include <hip/hip_runtime.h>
#include <hip/hip_bf16.h>

#define NTOK 577
#define CH 768
#define NH 12
#define HD 64
#define M_ROWS 9232      // B * N
#define NPAD 592         // 37*16  (n pitch of score buffer)
#define MPAD 608         // 19*32  (m pitch of score buffer)

typedef _Float16 f16x8 __attribute__((ext_vector_type(8)));
typedef float f32x4 __attribute__((ext_vector_type(4)));

__device__ __forceinline__ float ldin(const void* p, size_t i, bool f32) {
  return f32 ? ((const float*)p)[i]
             : __bfloat162float(((const __hip_bfloat16*)p)[i]);
}

// ---- Kernel 0: detect input dtype (fp32 vs bf16) from bit patterns.
__global__ void detect_dtype(const unsigned short* __restrict__ xs,
                             int* __restrict__ flag) {
  __shared__ int cnt;
  if (threadIdx.x == 0) cnt = 0;
  __syncthreads();
  int local = 0;
  for (int i = threadIdx.x; i < 4096; i += 256) {
    unsigned int u = xs[2 * i];
    unsigned int e = (u >> 7) & 0xFFu;
    if (e >= 140u) local++;
  }
  atomicAdd(&cnt, local);
  __syncthreads();
  if (threadIdx.x == 0) *flag = (cnt > 100) ? 1 : 0;
}

// ---- Kernel 1: qkv = x @ Wqkv^T, scatter to q,k [b][h][n][d] fp16 and
// vT [b][h][d][MPAD] fp16 (transposed for PV MFMA B-operand).
__global__ __launch_bounds__(256) void gemm_qkv(
    const void* __restrict__ X, const void* __restrict__ W,
    const int* __restrict__ flagp,
    _Float16* __restrict__ q, _Float16* __restrict__ k,
    _Float16* __restrict__ vT)
{
  const bool f32 = (*flagp != 0);
  __shared__ float As[16][65];
  __shared__ float Bs[16][65];
  const int m0 = blockIdx.y * 64;
  const int o0 = blockIdx.x * 64;
  const int tid = threadIdx.x;
  const int tx = tid & 15, ty = tid >> 4;
  const int lr = tid >> 2;
  const int lc = (tid & 3) << 2;
  float acc[4][4] = {};
  for (int k0 = 0; k0 < CH; k0 += 16) {
    int m = m0 + lr;
    if (m < M_ROWS) {
      size_t base = (size_t)m * CH + k0 + lc;
      #pragma unroll
      for (int j = 0; j < 4; ++j) As[lc + j][lr] = ldin(X, base + j, f32);
    } else {
      #pragma unroll
      for (int j = 0; j < 4; ++j) As[lc + j][lr] = 0.f;
    }
    size_t bbase = (size_t)(o0 + lr) * CH + k0 + lc;
    #pragma unroll
    for (int j = 0; j < 4; ++j) Bs[lc + j][lr] = ldin(W, bbase + j, f32);
    __syncthreads();
    #pragma unroll
    for (int kk = 0; kk < 16; ++kk) {
      float a[4], bb[4];
      #pragma unroll
      for (int i = 0; i < 4; ++i) a[i] = As[kk][ty * 4 + i];
      #pragma unroll
      for (int j = 0; j < 4; ++j) bb[j] = Bs[kk][tx * 4 + j];
      #pragma unroll
      for (int i = 0; i < 4; ++i)
        #pragma unroll
        for (int j = 0; j < 4; ++j) acc[i][j] += a[i] * bb[j];
    }
    __syncthreads();
  }
  #pragma unroll
  for (int i = 0; i < 4; ++i) {
    int m = m0 + ty * 4 + i;
    if (m >= M_ROWS) continue;
    int b = m / NTOK, n = m - b * NTOK;
    #pragma unroll
    for (int j = 0; j < 4; ++j) {
      int o = o0 + tx * 4 + j;
      int t = o / CH, rem = o - t * CH;
      int h = rem >> 6, dd = rem & 63;
      _Float16 val = (_Float16)acc[i][j];
      if (t == 0)
        q[((size_t)(b * NH + h) * NTOK + n) * HD + dd] = val;
      else if (t == 1)
        k[((size_t)(b * NH + h) * NTOK + n) * HD + dd] = val;
      else
        vT[((size_t)(b * NH + h) * HD + dd) * MPAD + n] = val;
    }
  }
}

// ---- zero the m-pad of vT (m in [577,608)) so PV K-loop needs no predicate.
__global__ void zerofill_vt(_Float16* __restrict__ vT) {
  int r = blockIdx.x * 8 + (threadIdx.x >> 5);
  int c = threadIdx.x & 31;
  if (r < 16 * NH * HD && c < MPAD - NTOK)
    vT[(size_t)r * MPAD + NTOK + c] = (_Float16)0.f;
}

// ---- Kernel 2: QK^T (all 12 heads) + Wpre mix, MFMA 16x16x32 f16.
// Writes logits S1P[bl][g][n(592)][m(608)] fp16 for m<577 (pad filled by K3).
__global__ __launch_bounds__(256) void qk_mix(
    const _Float16* __restrict__ q, const _Float16* __restrict__ k,
    const void* __restrict__ Wpre, const int* __restrict__ flagp,
    _Float16* __restrict__ S1P, int b0)
{
  const bool f32 = (*flagp != 0);
  __shared__ float wp[NH * NH];
  const int tid = threadIdx.x;
  if (tid < NH * NH) wp[tid] = ldin(Wpre, tid, f32) * 0.125f;  // fold scale
  __syncthreads();
  const int lane = tid & 63, wave = tid >> 6;
  const int quad = lane >> 4, l16 = lane & 15;
  const int bl = blockIdx.z, b = b0 + bl;
  const int n0 = blockIdx.y * 16;
  const int m0 = blockIdx.x * 64 + wave * 16;
  const int nq = min(n0 + l16, NTOK - 1);
  const int mk = min(m0 + l16, NTOK - 1);
  const size_t qbase = ((size_t)b * NH * NTOK + nq) * HD + quad * 8;
  const size_t kbase = ((size_t)b * NH * NTOK + mk) * HD + quad * 8;
  f32x4 acc[NH];
  #pragma unroll
  for (int h = 0; h < NH; ++h) {
    const size_t ho = (size_t)h * NTOK * HD;
    f16x8 a0 = *(const f16x8*)(q + qbase + ho);
    f16x8 bb0 = *(const f16x8*)(k + kbase + ho);
    f16x8 a1 = *(const f16x8*)(q + qbase + ho + 32);
    f16x8 bb1 = *(const f16x8*)(k + kbase + ho + 32);
    f32x4 z = {0.f, 0.f, 0.f, 0.f};
    z = __builtin_amdgcn_mfma_f32_16x16x32_f16(a0, bb0, z, 0, 0, 0);
    acc[h] = __builtin_amdgcn_mfma_f32_16x16x32_f16(a1, bb1, z, 0, 0, 0);
  }
  const int col = m0 + l16;
  #pragma unroll
  for (int g = 0; g < NH; ++g) {
    f32x4 s = {0.f, 0.f, 0.f, 0.f};
    #pragma unroll
    for (int h = 0; h < NH; ++h) {
      float w = wp[g * NH + h];
      s[0] += w * acc[h][0]; s[1] += w * acc[h][1];
      s[2] += w * acc[h][2]; s[3] += w * acc[h][3];
    }
    size_t base = ((size_t)(bl * NH + g) * NPAD + n0 + quad * 4) * MPAD + col;
    #pragma unroll
    for (int r = 0; r < 4; ++r) {
      int row = n0 + quad * 4 + r;
      if (row < NTOK && col < NTOK)
        S1P[base + (size_t)r * MPAD] = (_Float16)s[r];
    }
  }
}

// ---- Kernel 3: per (b,n): softmax over m + Wpost/rowsum mix, in-place on S1P.
// Writes zeros into m-pad [577,608).
__global__ __launch_bounds__(256) void softmax_mix(
    const void* __restrict__ Wpost, const int* __restrict__ flagp,
    _Float16* __restrict__ S1P)
{
  const bool f32 = (*flagp != 0);
  __shared__ float Sb[NH][NTOK + 7];
  __shared__ float W2[NH * NH];
  __shared__ float rowsum[NH];
  const int tid = threadIdx.x;
  const int bl = blockIdx.x / NTOK;
  const int n = blockIdx.x - bl * NTOK;
  #pragma unroll
  for (int g = 0; g < NH; ++g) {
    const _Float16* src = S1P + ((size_t)(bl * NH + g) * NPAD + n) * MPAD;
    for (int m = tid; m < NTOK; m += 256) Sb[g][m] = (float)src[m];
  }
  __syncthreads();
  const int wave = tid >> 6, lane = tid & 63;
  for (int g = wave; g < NH; g += 4) {
    float mx = -1e30f;
    for (int m = lane; m < NTOK; m += 64) mx = fmaxf(mx, Sb[g][m]);
    #pragma unroll
    for (int off = 32; off > 0; off >>= 1) mx = fmaxf(mx, __shfl_xor(mx, off));
    float sum = 0.f;
    for (int m = lane; m < NTOK; m += 64) {
      float e = __expf(Sb[g][m] - mx);
      Sb[g][m] = e; sum += e;
    }
    #pragma unroll
    for (int off = 32; off > 0; off >>= 1) sum += __shfl_xor(sum, off);
    if (lane == 0) rowsum[g] = sum;
  }
  __syncthreads();
  if (tid < NH * NH) W2[tid] = ldin(Wpost, tid, f32) / rowsum[tid % NH];
  __syncthreads();
  #pragma unroll
  for (int g = 0; g < NH; ++g) {
    _Float16* dst = S1P + ((size_t)(bl * NH + g) * NPAD + n) * MPAD;
    for (int m = tid; m < MPAD; m += 256) {
      float v = 0.f;
      if (m < NTOK) {
        #pragma unroll
        for (int h = 0; h < NH; ++h) v += W2[g * NH + h] * Sb[h][m];
      }
      dst[m] = (_Float16)v;
    }
  }
}

// ---- Kernel 4: O = P @ V via MFMA; P rows from S1P, V from vT.
__global__ __launch_bounds__(256) void pv_gemm(
    const _Float16* __restrict__ S1P, const _Float16* __restrict__ vT,
    _Float16* __restrict__ o1, int b0)
{
  const int tid = threadIdx.x;
  const int lane = tid & 63, wave = tid >> 6;
  const int quad = lane >> 4, l16 = lane & 15;
  const int n0 = blockIdx.x * 16;
  const int bh = blockIdx.y;
  const int bl = bh / NH, h = bh - bl * NH;
  const int b = b0 + bl;
  const int d0 = wave * 16;
  const size_t abase = ((size_t)(bl * NH + h) * NPAD + n0 + l16) * MPAD + quad * 8;
  const size_t bbase = ((size_t)(b * NH + h) * HD + d0 + l16) * MPAD + quad * 8;
  f32x4 acc = {0.f, 0.f, 0.f, 0.f};
  for (int k0 = 0; k0 < MPAD; k0 += 32) {
    f16x8 a = *(const f16x8*)(S1P + abase + k0);
    f16x8 bv = *(const f16x8*)(vT + bbase + k0);
    acc = __builtin_amdgcn_mfma_f32_16x16x32_f16(a, bv, acc, 0, 0, 0);
  }
  #pragma unroll
  for (int r = 0; r < 4; ++r) {
    int row = n0 + quad * 4 + r;
    if (row < NTOK)
      o1[((size_t)b * NTOK + row) * CH + h * HD + d0 + l16] = (_Float16)acc[r];
  }
}

// ---- Kernel 5: out = o1 @ Wproj^T + bproj
__global__ __launch_bounds__(256) void gemm_proj(
    const _Float16* __restrict__ A, const void* __restrict__ W,
    const void* __restrict__ bias, const int* __restrict__ flagp,
    void* __restrict__ out)
{
  const bool f32 = (*flagp != 0);
  __shared__ float As[16][65];
  __shared__ float Bs[16][65];
  const int m0 = blockIdx.y * 64;
  const int o0 = blockIdx.x * 64;
  const int tid = threadIdx.x;
  const int tx = tid & 15, ty = tid >> 4;
  const int lr = tid >> 2;
  const int lc = (tid & 3) << 2;
  float acc[4][4] = {};
  for (int k0 = 0; k0 < CH; k0 += 16) {
    int m = m0 + lr;
    if (m < M_ROWS) {
      const _Float16* s = A + (size_t)m * CH + k0 + lc;
      #pragma unroll
      for (int j = 0; j < 4; ++j) As[lc + j][lr] = (float)s[j];
    } else {
      #pragma unroll
      for (int j = 0; j < 4; ++j) As[lc + j][lr] = 0.f;
    }
    size_t bbase = (size_t)(o0 + lr) * CH + k0 + lc;
    #pragma unroll
    for (int j = 0; j < 4; ++j) Bs[lc + j][lr] = ldin(W, bbase + j, f32);
    __syncthreads();
    #pragma unroll
    for (int kk = 0; kk < 16; ++kk) {
      float a[4], bb[4];
      #pragma unroll
      for (int i = 0; i < 4; ++i) a[i] = As[kk][ty * 4 + i];
      #pragma unroll
      for (int j = 0; j < 4; ++j) bb[j] = Bs[kk][tx * 4 + j];
      #pragma unroll
      for (int i = 0; i < 4; ++i)
        #pragma unroll
        for (int j = 0; j < 4; ++j) acc[i][j] += a[i] * bb[j];
    }
    __syncthreads();
  }
  #pragma unroll
  for (int i = 0; i < 4; ++i) {
    int m = m0 + ty * 4 + i;
    if (m >= M_ROWS) continue;
    #pragma unroll
    for (int j = 0; j < 4; ++j) {
      int o = o0 + tx * 4 + j;
      float val = acc[i][j] + ldin(bias, o, f32);
      if (f32) ((float*)out)[(size_t)m * CH + o] = val;
      else ((__hip_bfloat16*)out)[(size_t)m * CH + o] = __float2bfloat16(val);
    }
  }
}

extern "C" void kernel_launch(void* const* d_in, const int* in_sizes, int n_in,
                              void* d_out, int out_size, void* d_ws, size_t ws_size,
                              hipStream_t stream) {
  const void* x     = d_in[0];
  const void* Wqkv  = d_in[1];
  const void* Wproj = d_in[2];
  const void* bproj = d_in[3];
  const void* Wpre  = d_in[4];
  const void* Wpost = d_in[5];

  int* flag = (int*)d_ws;
  _Float16* ws = (_Float16*)((char*)d_ws + 16);
  const size_t QE  = (size_t)16 * NH * NTOK * HD;   // 7,090,176
  const size_t VTE = (size_t)16 * NH * HD * MPAD;   // 7,471,104
  _Float16* q   = ws;
  _Float16* k   = q + QE;
  _Float16* vT  = k + QE;
  _Float16* o1  = vT + VTE;
  _Float16* S1P = o1 + QE;

  // choose batch-chunk size for the score buffer based on actual ws_size
  const size_t fixedB = 16 + (3 * QE + VTE) * sizeof(_Float16);
  const size_t perB   = (size_t)NH * NPAD * MPAD * sizeof(_Float16); // 8,638,464
  int cb = 1;
  for (int c = 16; c >= 1; c >>= 1) {
    if (fixedB + (size_t)c * perB <= ws_size) { cb = c; break; }
  }

  dim3 blk(256);
  hipLaunchKernelGGL(detect_dtype, dim3(1), blk, 0, stream,
                     (const unsigned short*)x, flag);
  hipLaunchKernelGGL(gemm_qkv, dim3(36, 145), blk, 0, stream,
                     x, Wqkv, flag, q, k, vT);
  hipLaunchKernelGGL(zerofill_vt, dim3(16 * NH * HD / 8), blk, 0, stream, vT);
  for (int b0 = 0; b0 < 16; b0 += cb) {
    hipLaunchKernelGGL(qk_mix, dim3(10, 37, cb), blk, 0, stream,
                       q, k, Wpre, flag, S1P, b0);
    hipLaunchKernelGGL(softmax_mix, dim3(cb * NTOK), blk, 0, stream,
                       Wpost, flag, S1P);
    hipLaunchKernelGGL(pv_gemm, dim3(37, cb * NH), blk, 0, stream,
                       S1P, vT, o1, b0);
  }
  hipLaunchKernelGGL(gemm_proj, dim3(12, 145), blk, 0, stream,
                     o1, Wproj, bproj, flag, d_out);
}

// Round 4
// 676.739 us; speedup vs baseline: 8.4096x; 2.4997x over previous
//
#include <hip/hip_runtime.h>
#include <hip/hip_bf16.h>

#define NTOK 577
#define CH 768
#define NH 12
#define HD 64
#define M_ROWS 9232      // B * N
#define NPAD 592         // 37*16  (n pitch of score buffer)
#define MPAD 608         // 19*32  (m pitch of score buffer)
#define LDP 40           // padded LDS row pitch (f16) for GEMM tiles

typedef _Float16 f16x8 __attribute__((ext_vector_type(8)));
typedef float f32x4 __attribute__((ext_vector_type(4)));

__device__ __forceinline__ float bf2f(unsigned int u16) {
  union { unsigned int i; float f; } x; x.i = u16 << 16; return x.f;
}

__device__ __forceinline__ float ldin(const void* p, size_t i, bool f32) {
  return f32 ? ((const float*)p)[i]
             : __bfloat162float(((const __hip_bfloat16*)p)[i]);
}

// load 8 consecutive elements (fp32 or bf16 source) -> f16x8
__device__ __forceinline__ f16x8 ld8_cvt(const void* p, size_t idx, bool f32) {
  f16x8 r;
  if (f32) {
    const float* f = (const float*)p + idx;
    const float4 u = *(const float4*)f;
    const float4 v = *(const float4*)(f + 4);
    r[0]=(_Float16)u.x; r[1]=(_Float16)u.y; r[2]=(_Float16)u.z; r[3]=(_Float16)u.w;
    r[4]=(_Float16)v.x; r[5]=(_Float16)v.y; r[6]=(_Float16)v.z; r[7]=(_Float16)v.w;
  } else {
    const unsigned short* s = (const unsigned short*)p + idx;
    uint4 u = *(const uint4*)s;
    unsigned int w0=u.x, w1=u.y, w2=u.z, w3=u.w;
    r[0]=(_Float16)bf2f(w0&0xffffu); r[1]=(_Float16)bf2f(w0>>16);
    r[2]=(_Float16)bf2f(w1&0xffffu); r[3]=(_Float16)bf2f(w1>>16);
    r[4]=(_Float16)bf2f(w2&0xffffu); r[5]=(_Float16)bf2f(w2>>16);
    r[6]=(_Float16)bf2f(w3&0xffffu); r[7]=(_Float16)bf2f(w3>>16);
  }
  return r;
}

// ---- Kernel 0: detect input dtype (fp32 vs bf16) from bit patterns.
__global__ void detect_dtype(const unsigned short* __restrict__ xs,
                             int* __restrict__ flag) {
  __shared__ int cnt;
  if (threadIdx.x == 0) cnt = 0;
  __syncthreads();
  int local = 0;
  for (int i = threadIdx.x; i < 4096; i += 256) {
    unsigned int u = xs[2 * i];
    unsigned int e = (u >> 7) & 0xFFu;
    if (e >= 140u) local++;
  }
  atomicAdd(&cnt, local);
  __syncthreads();
  if (threadIdx.x == 0) *flag = (cnt > 100) ? 1 : 0;
}

// ---- Kernel 1: qkv = x @ Wqkv^T via MFMA 16x16x32 f16, 128x128 tiles.
// Scatters to q,k [b][h][n][d] f16 and vT [b][h][d][MPAD] f16.
__global__ __launch_bounds__(256) void gemm_qkv_mfma(
    const void* __restrict__ X, const void* __restrict__ W,
    const int* __restrict__ flagp,
    _Float16* __restrict__ q, _Float16* __restrict__ k,
    _Float16* __restrict__ vT)
{
  const bool f32 = (*flagp != 0);
  __shared__ _Float16 As[128 * LDP];
  __shared__ _Float16 Bs[128 * LDP];
  const int tid = threadIdx.x;
  const int lane = tid & 63, wave = tid >> 6;
  const int quad = lane >> 4, l16 = lane & 15;
  const int wm = wave & 1, wo = wave >> 1;
  const int m0 = blockIdx.y * 128;
  const int bx = blockIdx.x;
  const int t = bx / 6;                    // 0=q 1=k 2=v
  const int o0 = bx * 128;                 // channel in [0,2304)
  const int o0loc = o0 - t * CH;           // channel within head-block [0,768)

  // staging coords: it in {0,1}: row = it*64 + tid>>2, col = (tid&3)*8
  const int srow = tid >> 2;
  const int scol = (tid & 3) * 8;
  const int arow0 = min(m0 + srow, M_ROWS - 1);
  const int arow1 = min(m0 + srow + 64, M_ROWS - 1);
  const int brow0 = o0 + srow;
  const int brow1 = o0 + srow + 64;

  f16x8 ra[2], rb[2];
  ra[0] = ld8_cvt(X, (size_t)arow0 * CH + scol, f32);
  ra[1] = ld8_cvt(X, (size_t)arow1 * CH + scol, f32);
  rb[0] = ld8_cvt(W, (size_t)brow0 * CH + scol, f32);
  rb[1] = ld8_cvt(W, (size_t)brow1 * CH + scol, f32);

  f32x4 acc[4][4] = {};
  for (int ks = 0; ks < CH / 32; ++ks) {
    __syncthreads();
    *(f16x8*)&As[(srow)      * LDP + scol] = ra[0];
    *(f16x8*)&As[(srow + 64) * LDP + scol] = ra[1];
    *(f16x8*)&Bs[(srow)      * LDP + scol] = rb[0];
    *(f16x8*)&Bs[(srow + 64) * LDP + scol] = rb[1];
    __syncthreads();
    if (ks + 1 < CH / 32) {
      int kc = (ks + 1) * 32 + scol;
      ra[0] = ld8_cvt(X, (size_t)arow0 * CH + kc, f32);
      ra[1] = ld8_cvt(X, (size_t)arow1 * CH + kc, f32);
      rb[0] = ld8_cvt(W, (size_t)brow0 * CH + kc, f32);
      rb[1] = ld8_cvt(W, (size_t)brow1 * CH + kc, f32);
    }
    f16x8 af[4], bf_[4];
    #pragma unroll
    for (int i = 0; i < 4; ++i)
      af[i] = *(const f16x8*)&As[(wm * 64 + i * 16 + l16) * LDP + quad * 8];
    #pragma unroll
    for (int j = 0; j < 4; ++j)
      bf_[j] = *(const f16x8*)&Bs[(wo * 64 + j * 16 + l16) * LDP + quad * 8];
    #pragma unroll
    for (int i = 0; i < 4; ++i)
      #pragma unroll
      for (int j = 0; j < 4; ++j)
        acc[i][j] = __builtin_amdgcn_mfma_f32_16x16x32_f16(af[i], bf_[j], acc[i][j], 0, 0, 0);
  }

  #pragma unroll
  for (int i = 0; i < 4; ++i) {
    #pragma unroll
    for (int rr = 0; rr < 4; ++rr) {
      int m = m0 + wm * 64 + i * 16 + quad * 4 + rr;
      if (m >= M_ROWS) continue;
      int b = m / NTOK, n = m - b * NTOK;
      #pragma unroll
      for (int j = 0; j < 4; ++j) {
        int o = o0loc + wo * 64 + j * 16 + l16;
        int h = o >> 6, dd = o & 63;
        _Float16 val = (_Float16)acc[i][j][rr];
        if (t == 0)
          q[((size_t)(b * NH + h) * NTOK + n) * HD + dd] = val;
        else if (t == 1)
          k[((size_t)(b * NH + h) * NTOK + n) * HD + dd] = val;
        else
          vT[((size_t)(b * NH + h) * HD + dd) * MPAD + n] = val;
      }
    }
  }
}

// ---- zero the m-pad of vT (m in [577,608)).
__global__ void zerofill_vt(_Float16* __restrict__ vT) {
  int r = blockIdx.x * 8 + (threadIdx.x >> 5);
  int c = threadIdx.x & 31;
  if (r < 16 * NH * HD && c < MPAD - NTOK)
    vT[(size_t)r * MPAD + NTOK + c] = (_Float16)0.f;
}

// ---- Kernel 2: QK^T (all 12 heads) + Wpre mix, MFMA 16x16x32 f16.
__global__ __launch_bounds__(256) void qk_mix(
    const _Float16* __restrict__ q, const _Float16* __restrict__ k,
    const void* __restrict__ Wpre, const int* __restrict__ flagp,
    _Float16* __restrict__ S1P, int b0)
{
  const bool f32 = (*flagp != 0);
  __shared__ float wp[NH * NH];
  const int tid = threadIdx.x;
  if (tid < NH * NH) wp[tid] = ldin(Wpre, tid, f32) * 0.125f;  // fold scale
  __syncthreads();
  const int lane = tid & 63, wave = tid >> 6;
  const int quad = lane >> 4, l16 = lane & 15;
  const int bl = blockIdx.z, b = b0 + bl;
  const int n0 = blockIdx.y * 16;
  const int m0 = blockIdx.x * 64 + wave * 16;
  const int nq = min(n0 + l16, NTOK - 1);
  const int mk = min(m0 + l16, NTOK - 1);
  const size_t qbase = ((size_t)b * NH * NTOK + nq) * HD + quad * 8;
  const size_t kbase = ((size_t)b * NH * NTOK + mk) * HD + quad * 8;
  f32x4 acc[NH];
  #pragma unroll
  for (int h = 0; h < NH; ++h) {
    const size_t ho = (size_t)h * NTOK * HD;
    f16x8 a0 = *(const f16x8*)(q + qbase + ho);
    f16x8 bb0 = *(const f16x8*)(k + kbase + ho);
    f16x8 a1 = *(const f16x8*)(q + qbase + ho + 32);
    f16x8 bb1 = *(const f16x8*)(k + kbase + ho + 32);
    f32x4 z = {0.f, 0.f, 0.f, 0.f};
    z = __builtin_amdgcn_mfma_f32_16x16x32_f16(a0, bb0, z, 0, 0, 0);
    acc[h] = __builtin_amdgcn_mfma_f32_16x16x32_f16(a1, bb1, z, 0, 0, 0);
  }
  const int col = m0 + l16;
  #pragma unroll
  for (int g = 0; g < NH; ++g) {
    f32x4 s = {0.f, 0.f, 0.f, 0.f};
    #pragma unroll
    for (int h = 0; h < NH; ++h) {
      float w = wp[g * NH + h];
      s[0] += w * acc[h][0]; s[1] += w * acc[h][1];
      s[2] += w * acc[h][2]; s[3] += w * acc[h][3];
    }
    size_t base = ((size_t)(bl * NH + g) * NPAD + n0 + quad * 4) * MPAD + col;
    #pragma unroll
    for (int r = 0; r < 4; ++r) {
      int row = n0 + quad * 4 + r;
      if (row < NTOK && col < NTOK)
        S1P[base + (size_t)r * MPAD] = (_Float16)s[r];
    }
  }
}

// ---- Kernel 3: per (b,n): softmax over m + Wpost/rowsum mix, in-place.
__global__ __launch_bounds__(256) void softmax_mix(
    const void* __restrict__ Wpost, const int* __restrict__ flagp,
    _Float16* __restrict__ S1P)
{
  const bool f32 = (*flagp != 0);
  __shared__ float Sb[NH][NTOK + 7];
  __shared__ float W2[NH * NH];
  __shared__ float rowsum[NH];
  const int tid = threadIdx.x;
  const int bl = blockIdx.x / NTOK;
  const int n = blockIdx.x - bl * NTOK;
  #pragma unroll
  for (int g = 0; g < NH; ++g) {
    const _Float16* src = S1P + ((size_t)(bl * NH + g) * NPAD + n) * MPAD;
    for (int m = tid; m < NTOK; m += 256) Sb[g][m] = (float)src[m];
  }
  __syncthreads();
  const int wave = tid >> 6, lane = tid & 63;
  for (int g = wave; g < NH; g += 4) {
    float mx = -1e30f;
    for (int m = lane; m < NTOK; m += 64) mx = fmaxf(mx, Sb[g][m]);
    #pragma unroll
    for (int off = 32; off > 0; off >>= 1) mx = fmaxf(mx, __shfl_xor(mx, off));
    float sum = 0.f;
    for (int m = lane; m < NTOK; m += 64) {
      float e = __expf(Sb[g][m] - mx);
      Sb[g][m] = e; sum += e;
    }
    #pragma unroll
    for (int off = 32; off > 0; off >>= 1) sum += __shfl_xor(sum, off);
    if (lane == 0) rowsum[g] = sum;
  }
  __syncthreads();
  if (tid < NH * NH) W2[tid] = ldin(Wpost, tid, f32) / rowsum[tid % NH];
  __syncthreads();
  #pragma unroll
  for (int g = 0; g < NH; ++g) {
    _Float16* dst = S1P + ((size_t)(bl * NH + g) * NPAD + n) * MPAD;
    for (int m = tid; m < MPAD; m += 256) {
      float v = 0.f;
      if (m < NTOK) {
        #pragma unroll
        for (int h = 0; h < NH; ++h) v += W2[g * NH + h] * Sb[h][m];
      }
      dst[m] = (_Float16)v;
    }
  }
}

// ---- Kernel 4: O = P @ V via MFMA; P rows from S1P, V from vT.
__global__ __launch_bounds__(256) void pv_gemm(
    const _Float16* __restrict__ S1P, const _Float16* __restrict__ vT,
    _Float16* __restrict__ o1, int b0)
{
  const int tid = threadIdx.x;
  const int lane = tid & 63, wave = tid >> 6;
  const int quad = lane >> 4, l16 = lane & 15;
  const int n0 = blockIdx.x * 16;
  const int bh = blockIdx.y;
  const int bl = bh / NH, h = bh - bl * NH;
  const int b = b0 + bl;
  const int d0 = wave * 16;
  const size_t abase = ((size_t)(bl * NH + h) * NPAD + n0 + l16) * MPAD + quad * 8;
  const size_t bbase = ((size_t)(b * NH + h) * HD + d0 + l16) * MPAD + quad * 8;
  f32x4 acc = {0.f, 0.f, 0.f, 0.f};
  for (int k0 = 0; k0 < MPAD; k0 += 32) {
    f16x8 a = *(const f16x8*)(S1P + abase + k0);
    f16x8 bv = *(const f16x8*)(vT + bbase + k0);
    acc = __builtin_amdgcn_mfma_f32_16x16x32_f16(a, bv, acc, 0, 0, 0);
  }
  #pragma unroll
  for (int r = 0; r < 4; ++r) {
    int row = n0 + quad * 4 + r;
    if (row < NTOK)
      o1[((size_t)b * NTOK + row) * CH + h * HD + d0 + l16] = (_Float16)acc[r];
  }
}

// ---- Kernel 5: out = o1 @ Wproj^T + bproj via MFMA, 128x128 tiles.
__global__ __launch_bounds__(256) void gemm_proj_mfma(
    const _Float16* __restrict__ A, const void* __restrict__ W,
    const void* __restrict__ bias, const int* __restrict__ flagp,
    void* __restrict__ out)
{
  const bool f32 = (*flagp != 0);
  __shared__ _Float16 As[128 * LDP];
  __shared__ _Float16 Bs[128 * LDP];
  const int tid = threadIdx.x;
  const int lane = tid & 63, wave = tid >> 6;
  const int quad = lane >> 4, l16 = lane & 15;
  const int wm = wave & 1, wo = wave >> 1;
  const int m0 = blockIdx.y * 128;
  const int o0 = blockIdx.x * 128;

  const int srow = tid >> 2;
  const int scol = (tid & 3) * 8;
  const int arow0 = min(m0 + srow, M_ROWS - 1);
  const int arow1 = min(m0 + srow + 64, M_ROWS - 1);
  const int brow0 = o0 + srow;
  const int brow1 = o0 + srow + 64;

  f16x8 ra[2], rb[2];
  ra[0] = *(const f16x8*)(A + (size_t)arow0 * CH + scol);
  ra[1] = *(const f16x8*)(A + (size_t)arow1 * CH + scol);
  rb[0] = ld8_cvt(W, (size_t)brow0 * CH + scol, f32);
  rb[1] = ld8_cvt(W, (size_t)brow1 * CH + scol, f32);

  f32x4 acc[4][4] = {};
  for (int ks = 0; ks < CH / 32; ++ks) {
    __syncthreads();
    *(f16x8*)&As[(srow)      * LDP + scol] = ra[0];
    *(f16x8*)&As[(srow + 64) * LDP + scol] = ra[1];
    *(f16x8*)&Bs[(srow)      * LDP + scol] = rb[0];
    *(f16x8*)&Bs[(srow + 64) * LDP + scol] = rb[1];
    __syncthreads();
    if (ks + 1 < CH / 32) {
      int kc = (ks + 1) * 32 + scol;
      ra[0] = *(const f16x8*)(A + (size_t)arow0 * CH + kc);
      ra[1] = *(const f16x8*)(A + (size_t)arow1 * CH + kc);
      rb[0] = ld8_cvt(W, (size_t)brow0 * CH + kc, f32);
      rb[1] = ld8_cvt(W, (size_t)brow1 * CH + kc, f32);
    }
    f16x8 af[4], bf_[4];
    #pragma unroll
    for (int i = 0; i < 4; ++i)
      af[i] = *(const f16x8*)&As[(wm * 64 + i * 16 + l16) * LDP + quad * 8];
    #pragma unroll
    for (int j = 0; j < 4; ++j)
      bf_[j] = *(const f16x8*)&Bs[(wo * 64 + j * 16 + l16) * LDP + quad * 8];
    #pragma unroll
    for (int i = 0; i < 4; ++i)
      #pragma unroll
      for (int j = 0; j < 4; ++j)
        acc[i][j] = __builtin_amdgcn_mfma_f32_16x16x32_f16(af[i], bf_[j], acc[i][j], 0, 0, 0);
  }

  #pragma unroll
  for (int i = 0; i < 4; ++i) {
    #pragma unroll
    for (int rr = 0; rr < 4; ++rr) {
      int m = m0 + wm * 64 + i * 16 + quad * 4 + rr;
      if (m >= M_ROWS) continue;
      #pragma unroll
      for (int j = 0; j < 4; ++j) {
        int o = o0 + wo * 64 + j * 16 + l16;
        float val = acc[i][j][rr] + ldin(bias, o, f32);
        if (f32) ((float*)out)[(size_t)m * CH + o] = val;
        else ((__hip_bfloat16*)out)[(size_t)m * CH + o] = __float2bfloat16(val);
      }
    }
  }
}

extern "C" void kernel_launch(void* const* d_in, const int* in_sizes, int n_in,
                              void* d_out, int out_size, void* d_ws, size_t ws_size,
                              hipStream_t stream) {
  const void* x     = d_in[0];
  const void* Wqkv  = d_in[1];
  const void* Wproj = d_in[2];
  const void* bproj = d_in[3];
  const void* Wpre  = d_in[4];
  const void* Wpost = d_in[5];

  int* flag = (int*)d_ws;
  _Float16* ws = (_Float16*)((char*)d_ws + 16);
  const size_t QE  = (size_t)16 * NH * NTOK * HD;   // 7,090,176
  const size_t VTE = (size_t)16 * NH * HD * MPAD;   // 7,471,104
  _Float16* q   = ws;
  _Float16* k   = q + QE;
  _Float16* vT  = k + QE;
  _Float16* o1  = vT + VTE;
  _Float16* S1P = o1 + QE;

  const size_t fixedB = 16 + (3 * QE + VTE) * sizeof(_Float16);
  const size_t perB   = (size_t)NH * NPAD * MPAD * sizeof(_Float16);
  int cb = 1;
  for (int c = 16; c >= 1; c >>= 1) {
    if (fixedB + (size_t)c * perB <= ws_size) { cb = c; break; }
  }

  dim3 blk(256);
  hipLaunchKernelGGL(detect_dtype, dim3(1), blk, 0, stream,
                     (const unsigned short*)x, flag);
  hipLaunchKernelGGL(gemm_qkv_mfma, dim3(18, 73), blk, 0, stream,
                     x, Wqkv, flag, q, k, vT);
  hipLaunchKernelGGL(zerofill_vt, dim3(16 * NH * HD / 8), blk, 0, stream, vT);
  for (int b0 = 0; b0 < 16; b0 += cb) {
    hipLaunchKernelGGL(qk_mix, dim3(10, 37, cb), blk, 0, stream,
                       q, k, Wpre, flag, S1P, b0);
    hipLaunchKernelGGL(softmax_mix, dim3(cb * NTOK), blk, 0, stream,
                       Wpost, flag, S1P);
    hipLaunchKernelGGL(pv_gemm, dim3(37, cb * NH), blk, 0, stream,
                       S1P, vT, o1, b0);
  }
  hipLaunchKernelGGL(gemm_proj_mfma, dim3(6, 73), blk, 0, stream,
                     o1, Wproj, bproj, flag, d_out);
}